// Round 6
// baseline (536.788 us; speedup 1.0000x reference)
//
#include <hip/hip_runtime.h>

#define DHW   192
#define DHW2  (DHW*DHW)
#define TX    64           // lanes span x (one wave = one x-row)
#define TTY   4
#define YB    4            // output rows per thread
#define BY    (TTY*YB)     // 16
#define ZCH   8
#define NT    (TX*TTY)     // 256

// No LDS, no barriers: img is read directly through L1/L2 (block working set
// ~17 KB). All waves fully independent.
__global__ __launch_bounds__(NT, 4)
void mind3d_kernel(const float* __restrict__ img, float* __restrict__ out)
{
    const int lane = threadIdx.x;
    const int ty   = threadIdx.y;

    const int x0 = blockIdx.x * TX;
    const int y0 = blockIdx.y * BY;
    const int zi = blockIdx.z;
    const int nzc = DHW / ZCH;          // 24
    const int b  = zi / nzc;
    const int z0 = (zi - b*nzc) * ZCH;

    const float* imgb = img + (size_t)b * ((size_t)DHW * DHW2);

    const float a1 = 0.01831563889245986f;   // exp(-1/sigma^2)
    const float n1 = 1.0f/(1.0f + 2.0f*a1);
    const float norm3 = n1*n1*n1;

    const int gx = x0 + lane;
    // conv zero-pad masks (x-taps of the Gaussian)
    const float mL = (gx == 0)     ? 0.f : 1.f;
    const float mR = (gx == DHW-1) ? 0.f : 1.f;
    // zero-fill masks for x-halo VALUES (reproduce the old ring's zero halo;
    // addresses are clamped for safety, values masked to 0)
    const float v2L = (gx >= 2)     ? 1.f : 0.f;
    const float v1L = (gx >= 1)     ? 1.f : 0.f;
    const float v1R = (gx <= DHW-2) ? 1.f : 0.f;
    const float v2R = (gx <= DHW-3) ? 1.f : 0.f;
    const int wy = y0 + ty*YB;

    // per-lane clamped column offsets folded with row wy (floats)
    int vo[5];
    #pragma unroll
    for (int d = 0; d < 5; ++d) {
        int xx = gx + d - 2;
        xx = xx < 0 ? 0 : (xx > DHW-1 ? DHW-1 : xx);
        vo[d] = wy*DHW + xx;
    }

    // z-direction register state: smoothed S at z-1 (zm), z (zc), + ch0 carry
    float zm[YB][6], zc[YB][6], zS0[YB];
    #pragma unroll
    for (int j = 0; j < YB; ++j) {
        zS0[j] = 0.f;
        #pragma unroll
        for (int c = 0; c < 6; ++c) { zm[j][c] = 0.f; zc[j][c] = 0.f; }
    }

    for (int zs = z0 - 1; zs <= z0 + ZCH; ++zs) {
        const bool zok  = ((unsigned)zs < (unsigned)DHW);
        const bool pok  = (zs + 1 < DHW);           // zs+1 >= 0 always
        const bool warm = (zs == z0 - 1);           // only step with explicit ch1
        const float* cs = imgb + (size_t)(zok ? zs : 0) * DHW2;      // center slice
        const float* ps = imgb + (size_t)(pok ? zs + 1 : 0) * DHW2;  // z+1 slice
        const float* ms = imgb + (size_t)(z0 >= 2 ? z0 - 2 : 0) * DHW2; // warm only

        // rolling 3-row window of the center slice (A row needs 3 cols)
        float A1, A2, A3, B0, B1, B2, B3, B4;
        if (zok && wy - 2 >= 0) {
            A1 = cs[vo[1] - 2*DHW]*v1L; A2 = cs[vo[2] - 2*DHW]; A3 = cs[vo[3] - 2*DHW]*v1R;
        } else { A1 = 0.f; A2 = 0.f; A3 = 0.f; }
        if (zok && wy - 1 >= 0) {
            B0 = cs[vo[0] - DHW]*v2L; B1 = cs[vo[1] - DHW]*v1L; B2 = cs[vo[2] - DHW];
            B3 = cs[vo[3] - DHW]*v1R; B4 = cs[vo[4] - DHW]*v2R;
        } else { B0 = 0.f; B1 = 0.f; B2 = 0.f; B3 = 0.f; B4 = 0.f; }

        float T[3][6];                              // rotating x-conv rows
        const int zcout = zs - 1;
        const bool emitz = (zcout >= z0);

        #pragma unroll
        for (int k = 0; k < 6; ++k) {
            const int gr = wy - 1 + k;
            // C row = gr+1 = wy+k (>=0 always); zero-fill when OOB (wave-uniform)
            float C0, C1, C2, C3, C4;
            if (zok && (wy + k) < DHW) {
                C0 = cs[vo[0] + k*DHW]*v2L; C1 = cs[vo[1] + k*DHW]*v1L;
                C2 = cs[vo[2] + k*DHW];
                C3 = cs[vo[3] + k*DHW]*v1R; C4 = cs[vo[4] + k*DHW]*v2R;
            } else { C0 = 0.f; C1 = 0.f; C2 = 0.f; C3 = 0.f; C4 = 0.f; }
            // z+1 slice, row gr (rel row wy: k-1)
            float zpL, zpC, zpR;
            const bool rowok = ((unsigned)gr < (unsigned)DHW);
            if (pok && rowok) {
                zpL = ps[vo[1] + (k-1)*DHW]*v1L;
                zpC = ps[vo[2] + (k-1)*DHW];
                zpR = ps[vo[3] + (k-1)*DHW]*v1R;
            } else { zpL = 0.f; zpC = 0.f; zpR = 0.f; }

            const bool rok = zok && rowok;
            float* Tk = T[k % 3];

            // +z channel: gated by ROW only (raw form feeds the ch1 carry).
            // Out-of-volume slices read as zeros, so at zs=-1 this yields
            // x-smooth(img(0)^2), at zs=192 it yields 0.
            {
                float eL = zpL-B1, eC = zpC-B2, eR = zpR-B3;
                Tk[0] = rowok ? (a1*(eL*eL*mL + eR*eR*mR) + eC*eC) : 0.f;
            }
            if (rok) {
                float d0 = B1-B0, d1 = B2-B1, d2 = B3-B2, d3 = B4-B3;
                float q0 = d0*d0, q1 = d1*d1, q2 = d2*d2, q3 = d3*d3;
                float eL, eC, eR;
                eL = C1-B1;  eC = C2-B2;  eR = C3-B3;                    // +y
                Tk[2] = a1*(eL*eL*mL + eR*eR*mR) + eC*eC;
                eL = A1-B1;  eC = A2-B2;  eR = A3-B3;                    // -y
                Tk[3] = a1*(eL*eL*mL + eR*eR*mR) + eC*eC;
                Tk[4] = a1*(q1*mL + q3*mR) + q2;                         // +x
                Tk[5] = a1*(q0*mL + q2*mR) + q1;                         // -x
            } else {
                Tk[2]=0.f; Tk[3]=0.f; Tk[4]=0.f; Tk[5]=0.f;
            }
            if (warm) {                      // explicit -z channel, first step only
                float t1v = 0.f;
                if (rok) {
                    float zmLv = 0.f, zmCv = 0.f, zmRv = 0.f;
                    if (z0 >= 2) {           // slice z0-2 exists, else zeros
                        zmLv = ms[vo[1] + (k-1)*DHW]*v1L;
                        zmCv = ms[vo[2] + (k-1)*DHW];
                        zmRv = ms[vo[3] + (k-1)*DHW]*v1R;
                    }
                    float eL = zmLv-B1, eC = zmCv-B2, eR = zmRv-B3;
                    t1v = a1*(eL*eL*mL + eR*eR*mR) + eC*eC;
                }
                Tk[1] = t1v;
            }

            if (k >= 2) {
                const int j = k - 2;         // output row wy+j
                // raw s0: row-gated only; feeds the ch1 carry (S1(zs+1)=S0(zs))
                float s0 = a1*(T[(k-2)%3][0] + T[k%3][0]) + T[(k-1)%3][0];
                float s2 = a1*(T[(k-2)%3][2] + T[k%3][2]) + T[(k-1)%3][2];
                float s3 = a1*(T[(k-2)%3][3] + T[k%3][3]) + T[(k-1)%3][3];
                float s4 = a1*(T[(k-2)%3][4] + T[k%3][4]) + T[(k-1)%3][4];
                float s5 = a1*(T[(k-2)%3][5] + T[k%3][5]) + T[(k-1)%3][5];
                // S-carry for ch1; at zs==DHW force conv zero-pad (0)
                float s1 = warm ? (a1*(T[(k-2)%3][1] + T[k%3][1]) + T[(k-1)%3][1])
                                : (zok ? zS0[j] : 0.f);
                zS0[j] = s0;
                // ch0's OWN z-state must see S0==0 outside [0,DHW)
                float s0st = zok ? s0 : 0.f;
                float sp_[6] = {s0st, s1, s2, s3, s4, s5};

                if (emitz) {
                    float dp[6], sum = 0.f;
                    #pragma unroll
                    for (int c = 0; c < 6; ++c) {
                        dp[c] = norm3 * (a1*(zm[j][c] + sp_[c]) + zc[j][c]);
                        sum += dp[c];
                    }
                    float inv = 1.0f / (sum * (1.0f/6.0f) + 1e-8f);
                    float num[6], nsum = 0.f;
                    #pragma unroll
                    for (int c = 0; c < 6; ++c) {
                        num[c] = __expf(-dp[c] * inv);
                        nsum += num[c];
                    }
                    float rs = 1.0f / (nsum + 1e-8f);
                    size_t base = ((size_t)(6*b)*DHW + zcout) * (size_t)DHW2
                                + (size_t)(wy + j)*DHW + (size_t)gx;
                    #pragma unroll
                    for (int c = 0; c < 6; ++c)
                        __builtin_nontemporal_store(num[c]*rs,
                            &out[base + (size_t)c * ((size_t)DHW*DHW2)]);
                }
                #pragma unroll
                for (int c = 0; c < 6; ++c) { zm[j][c] = zc[j][c]; zc[j][c] = sp_[c]; }
            }
            A1=B1; A2=B2; A3=B3;
            B0=C0; B1=C1; B2=C2; B3=C3; B4=C4;
        }
    }
}

extern "C" void kernel_launch(void* const* d_in, const int* in_sizes, int n_in,
                              void* d_out, int out_size, void* d_ws, size_t ws_size,
                              hipStream_t stream)
{
    const float* img = (const float*)d_in[0];
    float* out = (float*)d_out;
    dim3 block(TX, TTY, 1);
    dim3 grid(DHW/TX, DHW/BY, 2*(DHW/ZCH));   // 3 x 12 x 48 = 1728 blocks
    hipLaunchKernelGGL(mind3d_kernel, grid, block, 0, stream, img, out);
}